// Round 8
// baseline (694.828 us; speedup 1.0000x reference)
//
#include <hip/hip_runtime.h>

// DecoderLSTM: B=4096, T=128 (127 steps), H=128, 4H=512, V=30, E=256.
// R8: occupancy-tier attack. Total regs <= 128 (=> 4 waves/SIMD) with 8-wave
// 512-thr blocks so TWO blocks co-schedule per CU (R5-R7 evidence: tier =
// total VGPR+AGPR; 9-wave blocks at ~132 regs lock to 1 WG/CU).
// 512 blocks x 8 rows. M=8 on the 16-row MFMA; pointwise runs full-density
// via R6's (correctness-proven) shfl redistribution: quads 2-3 receive
// p={2,3} cells, every lane does 2 cells. Logits kt-split: each wave does
// +1 MFMA (kt=w&3, nt=w>>2) on h(t) in the SAME phase as gates; partials to
// LDS dbuf; wave 7 softmaxes the previous step's partials. One barrier/step.
// Register diet: af split 2+2, Xproj folded into pointwise (2 float4/lane,
// full density), acc zero-init, per-p shfl temps.

typedef __bf16 bf16x8 __attribute__((ext_vector_type(8)));
typedef float  f32x4  __attribute__((ext_vector_type(4)));

namespace {
constexpr int Bn = 4096, Tn = 128, Vn = 30, En = 256, Hn = 128, Gn = 512;
constexpr int WS_LOSS  = 0;
constexpr int WS_MASK  = 1;
constexpr int WS_CNT   = 2;
constexpr int WS_XPROJ = 16;                  // 30*512 fp32, layout [v][k][g]
constexpr int WS_WF_F  = WS_XPROJ + Vn * Gn;  // 65536 bf16 Whh-frags + 4096 bf16 Wlin-frags
constexpr int NBLK = 512;                     // 8 rows per block
}

__device__ __forceinline__ float fexp2(float x) { return __builtin_amdgcn_exp2f(x); }
__device__ __forceinline__ float frcp(float x)  { return __builtin_amdgcn_rcpf(x); }
__device__ __forceinline__ float sigf(float x)  { return frcp(1.f + fexp2(x * -1.44269504f)); }
__device__ __forceinline__ float tanh_(float x) { return 1.f - 2.f * frcp(fexp2(x * 2.88539008f) + 1.f); }

// ---- setup, 94 blocks x 256 (unchanged; zeroes loss/mask/cnt)
__global__ void k_setup(const float* __restrict__ emb, const float* __restrict__ W_ih,
                        const float* __restrict__ b_ih, const float* __restrict__ b_hh,
                        const float* __restrict__ W_hh, const float* __restrict__ W_lin,
                        float* __restrict__ ws) {
  const int bid = blockIdx.x, tid = threadIdx.x;
  if (bid < 60) {
    __shared__ __align__(16) float es[En];
    int v = bid >> 1;
    int j = ((bid & 1) << 8) + tid;   // j = g*128 + k
    es[tid] = emb[v * En + tid];
    __syncthreads();
    float a = b_ih[j] + b_hh[j];
    const float* wr = W_ih + j * En;
#pragma unroll 4
    for (int e = 0; e < En; e += 4) {
      float4 w = *(const float4*)(wr + e);
      float4 x = *(const float4*)(es + e);
      a += x.x * w.x + x.y * w.y + x.z * w.z + x.w * w.w;
    }
    ws[WS_XPROJ + v * Gn + (j & 127) * 4 + (j >> 7)] = a;
  } else if (bid < 92) {
    int fid = (bid - 60) * 256 + tid;  // 0..8191
    int l = fid & 63, kt = (fid >> 6) & 3, g = (fid >> 8) & 3, w = fid >> 10;
    int n  = (g * 8 + w) * 16 + (l & 15);
    int k0 = kt * 32 + (l >> 4) * 8;
    const float* src = W_hh + n * Hn + k0;
    union { __bf16 h[8]; uint4 u; } pk;
#pragma unroll
    for (int j = 0; j < 8; ++j) pk.h[j] = (__bf16)src[j];
    __bf16* wf = (__bf16*)(ws + WS_WF_F);
    *(uint4*)(wf + fid * 8) = pk.u;
  } else {
    int fid = (bid - 92) * 256 + tid;  // 0..511
    if (fid < 3) ws[fid] = 0.f;        // WS_LOSS, WS_MASK, WS_CNT
    int l = fid & 63, kt = (fid >> 6) & 3, n = fid >> 8;
    int col = n * 16 + (l & 15);
    int k0  = kt * 32 + (l >> 4) * 8;
    union { __bf16 h[8]; uint4 u; } pk;
#pragma unroll
    for (int j = 0; j < 8; ++j)
      pk.h[j] = (col < Vn) ? (__bf16)W_lin[col * Hn + k0 + j] : (__bf16)0.f;
    __bf16* wf = (__bf16*)(ws + WS_WF_F);
    *(uint4*)(wf + 65536 + fid * 8) = pk.u;
  }
}

// ---- main: 512 blocks x 512 threads (8 waves), 8 batch rows/block
__global__ __launch_bounds__(512, 4) void k_main(
    const int* __restrict__ inpt, const float* __restrict__ h0,
    const float* __restrict__ c0, const float* __restrict__ maskY,
    const float* __restrict__ b_lin, float* __restrict__ ws,
    float* __restrict__ out) {
  __shared__ __align__(16) __bf16 hbuf[2][16][136];  // rows 8-15 stay zero
  __shared__ int   tokL[8 * 129];
  __shared__ float maskL[8 * 132];
  __shared__ __align__(16) float lgP[2][8][256];     // [dbuf][kt*2+nt][lane*4+p]
  __shared__ float blinL[32];
  __shared__ float red[2];

  const float4* X4  = (const float4*)(ws + WS_XPROJ); // [v*128 + k] -> (i,f,g,o)
  const __bf16* wf  = (const __bf16*)(ws + WS_WF_F);
  const __bf16* wlf = wf + 65536;

  const int tid = threadIdx.x;
  const int w = tid >> 6, l = tid & 63, quad = l >> 4, lc = l & 15;
  const int row0 = blockIdx.x * 8;
  const int kh = w * 16 + lc;
  // pointwise row ownership after shfl: q0->{0,1}, q1->{4,5}, q2->{2,3}, q3->{6,7}
  const int prow0 = (quad < 2) ? quad * 4 : (quad - 2) * 4 + 2;
  const int lkt = w & 3, lnt = w >> 2;  // this wave's logits (kt, ntile)

  // staging
  for (int idx = tid; idx < 8 * Tn; idx += 512) {
    int r = idx >> 7, t = idx & 127;
    tokL[r * 129 + t]  = inpt[(row0 + r) * Tn + t];
    maskL[r * 132 + t] = maskY[(row0 + r) * Tn + t];
  }
  for (int idx = tid; idx < 8 * Hn; idx += 512) {
    int r = idx >> 7, k = idx & 127;
    hbuf[0][r][k] = (__bf16)h0[(row0 + r) * Hn + k];
  }
  for (int idx = tid; idx < 2 * 8 * 136; idx += 512) {  // zero rows 8-15, both bufs
    int pr = idx / (8 * 136), rem = idx - pr * (8 * 136);
    hbuf[pr][8 + rem / 136][rem % 136] = (__bf16)0.f;
  }
  if (tid < 32) blinL[tid] = (tid < Vn) ? b_lin[tid] : -1e30f;

  // persistent fragments: W_hh 16 frags (64 regs, expected in AGPRs) +
  // W_lin 1 frag (4 regs) per wave
  bf16x8 wreg[4][4];
#pragma unroll
  for (int g = 0; g < 4; ++g)
#pragma unroll
    for (int kt = 0; kt < 4; ++kt)
      wreg[g][kt] = __builtin_bit_cast(
          bf16x8, *(const uint4*)(wf + (((w * 4 + g) * 4 + kt) * 64 + l) * 8));
  bf16x8 wlin = __builtin_bit_cast(
      bf16x8, *(const uint4*)(wlf + ((lnt * 4 + lkt) * 64 + l) * 8));

  float creg[2];
#pragma unroll
  for (int p = 0; p < 2; ++p)
    creg[p] = c0[(row0 + prow0 + p) * Hn + kh];

  float mloc = 0.f;
  if (w == 6) {  // block-local mask sum: 8 rows x 128 = 256 float4
    float s = 0.f;
    const float4* m4 = (const float4*)(maskY + row0 * Tn);
#pragma unroll
    for (int i = 0; i < 4; ++i) s += m4[l + i * 64].x + m4[l + i * 64].y +
                                     m4[l + i * 64].z + m4[l + i * 64].w;
    mloc = s;
  }
  float ce_acc = 0.f;
  __syncthreads();

  for (int t = 0; t <= Tn; ++t) {  // gates: t<127, logits: 1<=t<=127, softmax: t>=2
    const int par = t & 1;
    const __bf16* hc = &hbuf[par][0][0];
    __bf16*       hn = &hbuf[par ^ 1][0][0];
    const bool do_g = (t < Tn - 1);
    const bool do_l = (t >= 1 && t <= Tn - 1);

    if (t <= Tn - 1) {
      f32x4 acc[4] = {{0,0,0,0},{0,0,0,0},{0,0,0,0},{0,0,0,0}};
      f32x4 lacc   = {0,0,0,0};
      bf16x8 af[2];
      // first half: kt 0,1
#pragma unroll
      for (int kt = 0; kt < 2; ++kt)
        af[kt] = __builtin_bit_cast(
            bf16x8, *(const uint4*)(hc + lc * 136 + kt * 32 + quad * 8));
      if (do_g) {
#pragma unroll
        for (int g = 0; g < 4; ++g)
#pragma unroll
          for (int kt = 0; kt < 2; ++kt)
            acc[g] = __builtin_amdgcn_mfma_f32_16x16x32_bf16(af[kt], wreg[g][kt], acc[g], 0, 0, 0);
      }
      if (do_l && lkt < 2)
        lacc = __builtin_amdgcn_mfma_f32_16x16x32_bf16(af[lkt], wlin, lacc, 0, 0, 0);
      // second half: kt 2,3 (reuse af regs)
#pragma unroll
      for (int kt = 0; kt < 2; ++kt)
        af[kt] = __builtin_bit_cast(
            bf16x8, *(const uint4*)(hc + lc * 136 + (kt + 2) * 32 + quad * 8));
      if (do_g) {
#pragma unroll
        for (int g = 0; g < 4; ++g)
#pragma unroll
          for (int kt = 0; kt < 2; ++kt)
            acc[g] = __builtin_amdgcn_mfma_f32_16x16x32_bf16(af[kt], wreg[g][kt + 2], acc[g], 0, 0, 0);
      }
      if (do_l && lkt >= 2)
        lacc = __builtin_amdgcn_mfma_f32_16x16x32_bf16(af[lkt - 2], wlin, lacc, 0, 0, 0);

      if (do_l)  // dump logits partial (C-layout, no transform)
        *(f32x4*)&lgP[par][lkt * 2 + lnt][l * 4] = lacc;

      if (do_g) {
        // shfl redistribution + pointwise, one p at a time (small reg peak)
#pragma unroll
        for (int p = 0; p < 2; ++p) {
          float m0 = __shfl(acc[0][2 + p], l & 31);
          float m1 = __shfl(acc[1][2 + p], l & 31);
          float m2 = __shfl(acc[2][2 + p], l & 31);
          float m3 = __shfl(acc[3][2 + p], l & 31);
          int   r  = prow0 + p;
          float4 x = X4[tokL[r * 129 + t] * 128 + kh];
          float gi = ((quad < 2) ? acc[0][p] : m0) + x.x;
          float gf = ((quad < 2) ? acc[1][p] : m1) + x.y;
          float gg = ((quad < 2) ? acc[2][p] : m2) + x.z;
          float go = ((quad < 2) ? acc[3][p] : m3) + x.w;
          float c2 = sigf(gf) * creg[p] + sigf(gi) * tanh_(gg);
          float h2 = sigf(go) * tanh_(c2);
          creg[p] = c2;
          hn[r * 136 + kh] = (__bf16)h2;
        }
      }
    }

    // wave 7: softmax+CE of logits(t-1) (in lgP[par^1]); ref-step s = t-2
    if (w == 7 && t >= 2) {
      const float* P = &lgP[par ^ 1][0][0];
      int r = l >> 3, j = l & 7;       // 8 rows x 8 lanes, 4 vocab each
      float lg[4], mx = -3.4e38f;
#pragma unroll
      for (int i = 0; i < 4; ++i) {
        int v = j * 4 + i;
        int li = ((r >> 2) * 16 + (v & 15)) * 4 + (r & 3);
        float s = blinL[v];
#pragma unroll
        for (int kt = 0; kt < 4; ++kt) s += P[(kt * 2 + (v >> 4)) * 256 + li];
        lg[i] = s;
        mx = fmaxf(mx, s);
      }
      mx = fmaxf(mx, __shfl_xor(mx, 1));
      mx = fmaxf(mx, __shfl_xor(mx, 2));
      mx = fmaxf(mx, __shfl_xor(mx, 4));
      int y = tokL[r * 129 + (t - 1)];
      float e = 0.f, ly = 0.f;
#pragma unroll
      for (int i = 0; i < 4; ++i) {
        e += fexp2((lg[i] - mx) * 1.44269504f);
        ly += (j * 4 + i == y) ? lg[i] : 0.f;
      }
      e  += __shfl_xor(e, 1);  ly += __shfl_xor(ly, 1);
      e  += __shfl_xor(e, 2);  ly += __shfl_xor(ly, 2);
      e  += __shfl_xor(e, 4);  ly += __shfl_xor(ly, 4);
      if (j == 0) {
        float ce = (mx + __logf(e)) - ly;
        ce_acc += ce * maskL[r * 132 + (t - 2)];
      }
    }
    __syncthreads();  // the only barrier per step
  }

  // final reductions: wave 6 mask -> LDS; wave 7 reduces CE + finishes
  if (w == 6) {
#pragma unroll
    for (int off = 32; off > 0; off >>= 1) mloc += __shfl_down(mloc, off);
    if (l == 0) red[0] = mloc;
  }
  __syncthreads();
  if (w == 7) {
#pragma unroll
    for (int off = 32; off > 0; off >>= 1) ce_acc += __shfl_down(ce_acc, off);
    if (l == 0) {
      atomicAdd(ws + WS_LOSS, ce_acc);
      atomicAdd(ws + WS_MASK, red[0]);
      __threadfence();
      unsigned old = atomicAdd((unsigned*)(ws + WS_CNT), 1u);
      if (old == NBLK - 1) {  // last block publishes
        float lv  = atomicAdd(ws + WS_LOSS, 0.f);
        float mv2 = atomicAdd(ws + WS_MASK, 0.f);
        out[0] = lv / mv2;
      }
    }
  }
}

extern "C" void kernel_launch(void* const* d_in, const int* in_sizes, int n_in,
                              void* d_out, int out_size, void* d_ws, size_t ws_size,
                              hipStream_t stream) {
  const int*   inpt  = (const int*)  d_in[0];
  const float* h0    = (const float*)d_in[1];
  const float* c0    = (const float*)d_in[2];
  const float* maskY = (const float*)d_in[3];
  // d_in[4] = beta (unused)
  const float* emb   = (const float*)d_in[5];
  const float* W_ih  = (const float*)d_in[6];
  const float* b_ih  = (const float*)d_in[7];
  const float* W_hh  = (const float*)d_in[8];
  const float* b_hh  = (const float*)d_in[9];
  const float* W_lin = (const float*)d_in[10];
  const float* b_lin = (const float*)d_in[11];
  float* ws  = (float*)d_ws;
  float* out = (float*)d_out;

  hipLaunchKernelGGL(k_setup, dim3(94),   dim3(256), 0, stream,
                     emb, W_ih, b_ih, b_hh, W_hh, W_lin, ws);
  hipLaunchKernelGGL(k_main,  dim3(NBLK), dim3(512), 0, stream,
                     inpt, h0, c0, maskY, b_lin, ws, out);
}